// Round 1
// baseline (1877.109 us; speedup 1.0000x reference)
//
#include <hip/hip_runtime.h>

#define F 128
#define NB 20

__device__ __forceinline__ float silu_f(float x) {
    return x * (1.0f / (1.0f + __expf(-x)));
}

// Accumulate acc[R] += X[r0+r, :] @ W[:, j] for a 128-wide layer.
// X rows are read with lane-uniform addresses (scalar loads, SMEM pipe);
// W is read coalesced (each element once per block). R=16 rows/block
// amortizes the weight stream to 64KB/block.
template<int R>
__device__ __forceinline__ void gemm_acc(
    const float* __restrict__ X, const float* __restrict__ W,
    int r0, int rows, int j, float* acc)
{
    const float4* __restrict__ X4 = (const float4*)X;
    int rbase[R];
#pragma unroll
    for (int r = 0; r < R; ++r) {
        int rr = r0 + r;
        rbase[r] = (rr < rows ? rr : rows - 1) * 32;  // clamp tail rows (loads only)
    }
#pragma unroll 2
    for (int k4 = 0; k4 < 32; ++k4) {
        const int k = k4 * 4;
        const float w0 = W[(k + 0) * F + j];
        const float w1 = W[(k + 1) * F + j];
        const float w2 = W[(k + 2) * F + j];
        const float w3 = W[(k + 3) * F + j];
#pragma unroll
        for (int r = 0; r < R; ++r) {
            const float4 xv = X4[rbase[r] + k4];
            acc[r] = fmaf(xv.x, w0, acc[r]);
            acc[r] = fmaf(xv.y, w1, acc[r]);
            acc[r] = fmaf(xv.z, w2, acc[r]);
            acc[r] = fmaf(xv.w, w3, acc[r]);
        }
    }
}

// Y = act(X @ W (+ b)) for a [rows,128] x [128,128] layer.
template<bool SILU, bool BIAS>
__global__ __launch_bounds__(128) void gemm128_kernel(
    const float* __restrict__ X, const float* __restrict__ W,
    const float* __restrict__ b, float* __restrict__ Y, int rows)
{
    constexpr int R = 16;
    const int j = threadIdx.x;
    const int r0 = blockIdx.x * R;
    float acc[R];
    const float bj = BIAS ? b[j] : 0.0f;
#pragma unroll
    for (int r = 0; r < R; ++r) acc[r] = bj;
    gemm_acc<R>(X, W, r0, rows, j, acc);
#pragma unroll
    for (int r = 0; r < R; ++r) {
        const int row = r0 + r;
        if (row < rows) {
            float v = acc[r];
            if (SILU) v = silu_f(v);
            Y[(size_t)row * F + j] = v;
        }
    }
}

// Second layer of eq1 MLP fused with eq1 scatter:
// agg1[src[e], d, j] += (X[e]@W + b)[j] * disp_edge[e, d]
__global__ __launch_bounds__(128) void gemm128_scatter_eq1_kernel(
    const float* __restrict__ X, const float* __restrict__ W,
    const float* __restrict__ b,
    const float* __restrict__ disp_edge, const int* __restrict__ src,
    float* __restrict__ agg1, int rows)
{
    constexpr int R = 16;
    const int j = threadIdx.x;
    const int r0 = blockIdx.x * R;
    float acc[R];
    const float bj = b[j];
#pragma unroll
    for (int r = 0; r < R; ++r) acc[r] = bj;
    gemm_acc<R>(X, W, r0, rows, j, acc);
#pragma unroll
    for (int r = 0; r < R; ++r) {
        const int e = r0 + r;
        if (e < rows) {
            const int s = src[e];
            const float de0 = disp_edge[(size_t)e * 3 + 0];
            const float de1 = disp_edge[(size_t)e * 3 + 1];
            const float de2 = disp_edge[(size_t)e * 3 + 2];
            float* base = agg1 + (size_t)s * (3 * F) + j;
            atomicAdd(base,         acc[r] * de0);
            atomicAdd(base + F,     acc[r] * de1);
            atomicAdd(base + 2 * F, acc[r] * de2);
        }
    }
}

// Second layer of eq2 MLP fused with eq2 scatter:
// out_disp[src[e], d, j] += (X[e]@W + b)[j] * disp_node[dst[e], d, j]
__global__ __launch_bounds__(128) void gemm128_scatter_eq2_kernel(
    const float* __restrict__ X, const float* __restrict__ W,
    const float* __restrict__ b,
    const float* __restrict__ disp_node,
    const int* __restrict__ src, const int* __restrict__ dst,
    float* __restrict__ out_disp, int rows)
{
    constexpr int R = 16;
    const int j = threadIdx.x;
    const int r0 = blockIdx.x * R;
    float acc[R];
    const float bj = b[j];
#pragma unroll
    for (int r = 0; r < R; ++r) acc[r] = bj;
    gemm_acc<R>(X, W, r0, rows, j, acc);
#pragma unroll
    for (int r = 0; r < R; ++r) {
        const int e = r0 + r;
        if (e < rows) {
            const int s = src[e];
            const int d = dst[e];
            const float* dn = disp_node + (size_t)d * (3 * F) + j;
            float* base = out_disp + (size_t)s * (3 * F) + j;
            atomicAdd(base,         acc[r] * dn[0]);
            atomicAdd(base + F,     acc[r] * dn[F]);
            atomicAdd(base + 2 * F, acc[r] * dn[2 * F]);
        }
    }
}

// Edge embedding + invariant message + scatter into atom_new.
// m = (dist_edge[e]@emp_W + emp_b) * h[src] * h[dst]
__global__ __launch_bounds__(256) void edge_inv_kernel(
    const float* __restrict__ dist_edge, const float* __restrict__ emp_W,
    const float* __restrict__ emp_b, const float* __restrict__ h,
    const int* __restrict__ src, const int* __restrict__ dst,
    float* __restrict__ inv_msg, float* __restrict__ atom_new, int E)
{
    const int t = blockIdx.x * 256 + threadIdx.x;
    const int e = t >> 7;
    const int j = t & 127;
    if (e >= E) return;
    float acc = emp_b[j];
#pragma unroll
    for (int k = 0; k < NB; ++k)
        acc = fmaf(dist_edge[(size_t)e * NB + k], emp_W[k * F + j], acc);
    const int s = src[e];
    const int d = dst[e];
    const float m = acc * h[(size_t)s * F + j] * h[(size_t)d * F + j];
    inv_msg[(size_t)e * F + j] = m;
    atomicAdd(atom_new + (size_t)s * F + j, m);
}

// eq3 scatter: out_disp[src, d, j] += eq3_inv[dst, j] * agg1[dst, d, j]
__global__ __launch_bounds__(256) void edge_eq3_kernel(
    const float* __restrict__ eq3_inv, const float* __restrict__ agg1,
    const int* __restrict__ src, const int* __restrict__ dst,
    float* __restrict__ out_disp, int E)
{
    const int t = blockIdx.x * 256 + threadIdx.x;
    const int e = t >> 7;
    const int j = t & 127;
    if (e >= E) return;
    const int s = src[e];
    const int d = dst[e];
    const float g = eq3_inv[(size_t)d * F + j];
    const float* a = agg1 + (size_t)d * (3 * F) + j;
    float* o = out_disp + (size_t)s * (3 * F) + j;
    atomicAdd(o,         g * a[0]);
    atomicAdd(o + F,     g * a[F]);
    atomicAdd(o + 2 * F, g * a[2 * F]);
}

// ws/out initialization (ws is poisoned 0xAA before every launch).
__global__ void init_kernel(const float* __restrict__ atom,
                            const float* __restrict__ disp,
                            float* __restrict__ atom_new,
                            float* __restrict__ agg1,
                            float* __restrict__ out_disp,
                            int nF, int n3F)
{
    const int stride = gridDim.x * blockDim.x;
    for (int i = blockIdx.x * blockDim.x + threadIdx.x; i < n3F; i += stride) {
        agg1[i] = 0.0f;
        out_disp[i] = disp[i];
        if (i < nF) atom_new[i] = atom[i];
    }
}

__global__ void force_kernel(const float* __restrict__ force,
                             const float* __restrict__ agg1,
                             float* __restrict__ out_force, int n3F)
{
    const int stride = gridDim.x * blockDim.x;
    for (int i = blockIdx.x * blockDim.x + threadIdx.x; i < n3F; i += stride)
        out_force[i] = force[i] + agg1[i];
}

// Final per-node: u = mlp2(atom_new, upd) * sum_d(-force_out*disp_out);
// out_atom = LayerNorm(atom_new + u). One node per 128-thread block.
__global__ __launch_bounds__(128) void update_ln_kernel(
    const float* __restrict__ atom_new,
    const float* __restrict__ W1, const float* __restrict__ b1,
    const float* __restrict__ W2, const float* __restrict__ b2,
    const float* __restrict__ out_force, const float* __restrict__ out_disp,
    const float* __restrict__ ln_g, const float* __restrict__ ln_b,
    float* __restrict__ out_atom, int N)
{
    const int n = blockIdx.x;
    if (n >= N) return;
    const int j = threadIdx.x;
    __shared__ __align__(16) float hid[F];
    __shared__ float red[4];

    const float* x = atom_new + (size_t)n * F;
    const float4* x4 = (const float4*)x;
    float a1 = b1[j];
#pragma unroll 4
    for (int k4 = 0; k4 < 32; ++k4) {
        const float4 xv = x4[k4];
        const int k = 4 * k4;
        a1 = fmaf(xv.x, W1[(k + 0) * F + j], a1);
        a1 = fmaf(xv.y, W1[(k + 1) * F + j], a1);
        a1 = fmaf(xv.z, W1[(k + 2) * F + j], a1);
        a1 = fmaf(xv.w, W1[(k + 3) * F + j], a1);
    }
    hid[j] = silu_f(a1);
    __syncthreads();

    float a2 = b2[j];
    const float4* h4 = (const float4*)hid;
#pragma unroll 4
    for (int k4 = 0; k4 < 32; ++k4) {
        const float4 hv = h4[k4];
        const int k = 4 * k4;
        a2 = fmaf(hv.x, W2[(k + 0) * F + j], a2);
        a2 = fmaf(hv.y, W2[(k + 1) * F + j], a2);
        a2 = fmaf(hv.z, W2[(k + 2) * F + j], a2);
        a2 = fmaf(hv.w, W2[(k + 3) * F + j], a2);
    }

    const float* fo = out_force + (size_t)n * (3 * F) + j;
    const float* dl = out_disp + (size_t)n * (3 * F) + j;
    const float s = -(fo[0] * dl[0] + fo[F] * dl[F] + fo[2 * F] * dl[2 * F]);
    const float y = x[j] + a2 * s;

    float sy = y, syy = y * y;
#pragma unroll
    for (int m = 1; m < 64; m <<= 1) {
        sy  += __shfl_xor(sy, m);
        syy += __shfl_xor(syy, m);
    }
    if ((j & 63) == 0) {
        red[(j >> 6) * 2 + 0] = sy;
        red[(j >> 6) * 2 + 1] = syy;
    }
    __syncthreads();
    const float tsy  = red[0] + red[2];
    const float tsyy = red[1] + red[3];
    const float mu = tsy * (1.0f / F);
    float var = tsyy * (1.0f / F) - mu * mu;
    if (var < 0.0f) var = 0.0f;
    const float rstd = rsqrtf(var + 1e-5f);
    out_atom[(size_t)n * F + j] = (y - mu) * rstd * ln_g[j] + ln_b[j];
}

extern "C" void kernel_launch(void* const* d_in, const int* in_sizes, int n_in,
                              void* d_out, int out_size, void* d_ws, size_t ws_size,
                              hipStream_t stream)
{
    const float* atom_node  = (const float*)d_in[0];
    const float* force_node = (const float*)d_in[1];
    const float* disp_node  = (const float*)d_in[2];
    const float* disp_edge  = (const float*)d_in[3];
    const float* dist_edge  = (const float*)d_in[4];
    const int*   edge_index = (const int*)d_in[5];
    const float* nmp_W1 = (const float*)d_in[6];
    const float* nmp_b1 = (const float*)d_in[7];
    const float* nmp_W2 = (const float*)d_in[8];
    const float* nmp_b2 = (const float*)d_in[9];
    const float* emp_W  = (const float*)d_in[10];
    const float* emp_b  = (const float*)d_in[11];
    const float* eq1_W1 = (const float*)d_in[12];
    const float* eq1_b1 = (const float*)d_in[13];
    const float* eq1_W2 = (const float*)d_in[14];
    const float* eq1_b2 = (const float*)d_in[15];
    const float* eq2_W1 = (const float*)d_in[16];
    const float* eq2_b1 = (const float*)d_in[17];
    const float* eq2_W2 = (const float*)d_in[18];
    const float* eq2_b2 = (const float*)d_in[19];
    const float* eq3_W1 = (const float*)d_in[20];
    const float* eq3_W2 = (const float*)d_in[21];
    const float* upd_W1 = (const float*)d_in[22];
    const float* upd_b1 = (const float*)d_in[23];
    const float* upd_W2 = (const float*)d_in[24];
    const float* upd_b2 = (const float*)d_in[25];
    const float* ln_g   = (const float*)d_in[26];
    const float* ln_b   = (const float*)d_in[27];

    const int N = in_sizes[0] / F;       // 10000
    const int E = in_sizes[4] / NB;      // 200000
    const int* src = edge_index;
    const int* dst = edge_index + E;
    const int nF = N * F, n3F = N * 3 * F;

    float* out_atom  = (float*)d_out;
    float* out_force = out_atom + (size_t)nF;
    float* out_disp  = out_force + (size_t)n3F;

    // workspace layout (floats)
    float* ws = (float*)d_ws;
    float* h        = ws;                          // N*F
    float* atom_new = h + (size_t)nF;              // N*F
    float* agg1     = atom_new + (size_t)nF;       // N*3*F
    float* eq3i     = agg1 + (size_t)n3F;          // N*F
    float* inv_msg  = eq3i + (size_t)nF;           // E*F
    float* hid      = inv_msg + (size_t)E * F;     // CH*F (chunked hidden)

    // hidden-buffer chunk rows from remaining ws space (deterministic per ws_size
    // -> same launch count every call, graph-capture safe)
    const size_t fixed = (size_t)6 * nF + (size_t)E * F;
    long long avail = (long long)(ws_size / sizeof(float)) - (long long)fixed;
    long long ch_rows = (avail > 0 ? avail : 0) / F;
    ch_rows &= ~15LL;
    if (ch_rows < N) ch_rows = N;   // node passes need N rows of hid
    if (ch_rows > E) ch_rows = E;
    const int CH = (int)ch_rows;

    init_kernel<<<1024, 256, 0, stream>>>(atom_node, disp_node, atom_new, agg1,
                                          out_disp, nF, n3F);

    // h = mlp2(atom_node, nmp)
    gemm128_kernel<true,  true><<<(N + 15) / 16, 128, 0, stream>>>(atom_node, nmp_W1, nmp_b1, hid, N);
    gemm128_kernel<false, true><<<(N + 15) / 16, 128, 0, stream>>>(hid, nmp_W2, nmp_b2, h, N);

    // inv_message + atom_new scatter
    edge_inv_kernel<<<(E + 1) / 2, 256, 0, stream>>>(dist_edge, emp_W, emp_b, h,
                                                     src, dst, inv_msg, atom_new, E);

    // eq1: mlp2(inv_msg) * disp_edge -> agg1 (scatter by src)
    for (int c0 = 0; c0 < E; c0 += CH) {
        const int c = (E - c0 < CH) ? (E - c0) : CH;
        gemm128_kernel<true, true><<<(c + 15) / 16, 128, 0, stream>>>(
            inv_msg + (size_t)c0 * F, eq1_W1, eq1_b1, hid, c);
        gemm128_scatter_eq1_kernel<<<(c + 15) / 16, 128, 0, stream>>>(
            hid, eq1_W2, eq1_b2, disp_edge + (size_t)c0 * 3, src + c0, agg1, c);
    }
    // eq2: mlp2(inv_msg) * disp_node[dst] -> out_disp (scatter by src)
    for (int c0 = 0; c0 < E; c0 += CH) {
        const int c = (E - c0 < CH) ? (E - c0) : CH;
        gemm128_kernel<true, true><<<(c + 15) / 16, 128, 0, stream>>>(
            inv_msg + (size_t)c0 * F, eq2_W1, eq2_b1, hid, c);
        gemm128_scatter_eq2_kernel<<<(c + 15) / 16, 128, 0, stream>>>(
            hid, eq2_W2, eq2_b2, disp_node, src + c0, dst + c0, out_disp, c);
    }

    // force_out = force + agg1   (agg1 complete after eq1 loop)
    force_kernel<<<1024, 256, 0, stream>>>(force_node, agg1, out_force, n3F);

    // eq3_inv = mlp2_nobias(atom_new)
    gemm128_kernel<true,  false><<<(N + 15) / 16, 128, 0, stream>>>(atom_new, eq3_W1, nullptr, hid, N);
    gemm128_kernel<false, false><<<(N + 15) / 16, 128, 0, stream>>>(hid, eq3_W2, nullptr, eq3i, N);

    // eq3 scatter into out_disp
    edge_eq3_kernel<<<(E + 1) / 2, 256, 0, stream>>>(eq3i, agg1, src, dst, out_disp, E);

    // final invariant update + layernorm
    update_ln_kernel<<<N, 128, 0, stream>>>(atom_new, upd_W1, upd_b1, upd_W2, upd_b2,
                                            out_force, out_disp, ln_g, ln_b, out_atom, N);
}